// Round 5
// baseline (252.555 us; speedup 1.0000x reference)
//
#include <hip/hip_runtime.h>
#include <stdint.h>

#define QPF  127.0f
#define MINR 1e-6f

typedef int v4i __attribute__((ext_vector_type(4)));
typedef float f4v __attribute__((ext_vector_type(4)));
typedef _Float16 h4v __attribute__((ext_vector_type(4)));
typedef _Float16 h8 __attribute__((ext_vector_type(8)));
typedef signed char c8 __attribute__((ext_vector_type(8)));

// ---------- helpers ----------
__device__ __forceinline__ float wave_max64(float v) {
  v = fmaxf(v, __shfl_xor(v, 32, 64));
  v = fmaxf(v, __shfl_xor(v, 16, 64));
  v = fmaxf(v, __shfl_xor(v, 8, 64));
  v = fmaxf(v, __shfl_xor(v, 4, 64));
  v = fmaxf(v, __shfl_xor(v, 2, 64));
  v = fmaxf(v, __shfl_xor(v, 1, 64));
  return v;
}

// Exact-GELU via A&S 7.1.26 erf (|eps| <= 1.5e-7), branchless.
__device__ __forceinline__ float gelu_exact(float x) {
  float z = fabsf(x) * 0.70710678118654752440f;
  float t = __builtin_amdgcn_rcpf(fmaf(0.3275911f, z, 1.0f));
  float p = fmaf(fmaf(fmaf(fmaf(1.061405429f, t, -1.453152027f), t,
                           1.421413741f), t, -0.284496736f), t, 0.254829592f) * t;
  float e = __expf(-z * z);
  float erfz = fmaf(-p, e, 1.0f);
  float cdf = fmaf(0.5f, copysignf(erfz, x), 0.5f);
  return x * cdf;
}

// async global->LDS, 16B per lane; LDS dest is wave-uniform base + lane*16
__device__ __forceinline__ void gl2lds16(const void* g, void* l) {
  __builtin_amdgcn_global_load_lds(
      (const __attribute__((address_space(1))) int*)g,
      (__attribute__((address_space(3))) int*)l,
      16, 0, 0);
}

// XCD-aware bijective block remap (T1, m204 variant).
__device__ __forceinline__ int xcd_swizzle(int flat, int nwg) {
  const int xcd = flat & 7;
  const int idx = flat >> 3;
  const int q = nwg >> 3, r = nwg & 7;
  const int base = (xcd < r) ? xcd * (q + 1) : r * (q + 1) + (xcd - r) * q;
  return base + idx;
}

// ---------- fused pre-pass: w1/w2 amax partials + per-token x quant + amaxh zero ----
__global__ __launch_bounds__(256) void pre_kernel(
    const float* __restrict__ w1, const float* __restrict__ w2, int n4,
    const float* __restrict__ x, signed char* __restrict__ qx,
    float* __restrict__ sx, unsigned* __restrict__ amaxh,
    float* __restrict__ partial, int K, int nTok) {
  __shared__ float red[4];
  const int b = blockIdx.x;
  const int tid = threadIdx.x;
  const int lane = tid & 63, wvi = tid >> 6;

  if (b < 1024) {
    const float4* w4 = (const float4*)(b < 512 ? w1 : w2);
    const int bb = b & 511;
    float m = 0.f;
    for (int i = bb * 256 + tid; i < n4; i += 512 * 256) {
      float4 v = w4[i];
      m = fmaxf(m, fmaxf(fmaxf(fabsf(v.x), fabsf(v.y)),
                         fmaxf(fabsf(v.z), fabsf(v.w))));
    }
    m = wave_max64(m);
    if (lane == 0) red[wvi] = m;
    __syncthreads();
    if (tid == 0)
      partial[b] = fmaxf(fmaxf(red[0], red[1]), fmaxf(red[2], red[3]));
  } else {
    const int token = (b - 1024) * 4 + wvi;
    if (token < nTok) {
      const int k4 = K >> 2;  // 192 for D=768
      const float4* xr = (const float4*)(x + (size_t)token * K);
      float m = 0.f;
      for (int i = lane; i < k4; i += 64) {
        float4 v = xr[i];
        m = fmaxf(m, fmaxf(fmaxf(fabsf(v.x), fabsf(v.y)),
                           fmaxf(fabsf(v.z), fabsf(v.w))));
      }
      m = wave_max64(m);
      const float s = fmaxf(m, MINR) / QPF;
      const float rs = 1.0f / s;
      if (lane == 0) { sx[token] = s; amaxh[token] = 0u; }
      char4* q4 = (char4*)(qx + (size_t)token * K);
      for (int i = lane; i < k4; i += 64) {
        float4 v = xr[i];  // L1-hot reload
        char4 c;
        c.x = (signed char)(int)rintf(v.x * rs);
        c.y = (signed char)(int)rintf(v.y * rs);
        c.z = (signed char)(int)rintf(v.z * rs);
        c.w = (signed char)(int)rintf(v.w * rs);
        q4[i] = c;
      }
    }
  }
}

// ---------- weight quantize (reduces 512 partials itself; y selects tensor) ----------
__global__ __launch_bounds__(256) void wquant2_kernel(
    const float* __restrict__ w1, const float* __restrict__ w2, int n4,
    const float* __restrict__ partial, unsigned* __restrict__ wamax,
    signed char* __restrict__ q1, signed char* __restrict__ q2) {
  __shared__ float red[4];
  const int tid = threadIdx.x;
  const int lane = tid & 63, wvi = tid >> 6;
  const int y = blockIdx.y;
  float m = fmaxf(partial[y * 512 + tid], partial[y * 512 + 256 + tid]);
  m = wave_max64(m);
  if (lane == 0) red[wvi] = m;
  __syncthreads();
  const float M = fmaxf(fmaxf(red[0], red[1]), fmaxf(red[2], red[3]));
  if (blockIdx.x == 0 && tid == 0) wamax[y] = __float_as_uint(M);
  const float s = fmaxf(M, MINR) / QPF;
  const float rs = 1.0f / s;
  const float4* w4 = (const float4*)(y ? w2 : w1);
  char4* q4 = (char4*)(y ? q2 : q1);
  for (int i = blockIdx.x * 256 + tid; i < n4; i += gridDim.x * 256) {
    float4 v = w4[i];
    char4 c;
    c.x = (signed char)(int)rintf(v.x * rs);
    c.y = (signed char)(int)rintf(v.y * rs);
    c.z = (signed char)(int)rintf(v.z * rs);
    c.w = (signed char)(int)rintf(v.w * rs);
    q4[i] = c;
  }
}

// ---------- per-token h quantize: 4 tokens/block, one wave each ----------
__global__ __launch_bounds__(256) void hquant4_kernel(
    const _Float16* __restrict__ h, const unsigned* __restrict__ amaxbits,
    signed char* __restrict__ qh, float* __restrict__ sh, int K) {
  const int token = blockIdx.x * 4 + (threadIdx.x >> 6);
  const int lane = threadIdx.x & 63;
  const float s = fmaxf(__uint_as_float(amaxbits[token]), MINR) / QPF;
  const float rs = 1.0f / s;
  if (lane == 0) sh[token] = s;
  const h8* hr = (const h8*)(h + (size_t)token * K);
  c8* qr = (c8*)(qh + (size_t)token * K);
  for (int i = lane; i < (K >> 3); i += 64) {
    h8 v = hr[i];
    c8 c;
#pragma unroll
    for (int j = 0; j < 8; j++)
      c[j] = (signed char)(int)rintf((float)v[j] * rs);
    qr[i] = c;
  }
}

// 8 MFMAs for one mi-pair (a0 = frag mi=MI0, a1 = frag mi=MI1)
#define PHASE_MMA(MI0, MI1)                                                    \
  acc[MI0][0] = __builtin_amdgcn_mfma_i32_16x16x64_i8(b0, a0, acc[MI0][0], 0, 0, 0); \
  acc[MI0][1] = __builtin_amdgcn_mfma_i32_16x16x64_i8(b1, a0, acc[MI0][1], 0, 0, 0); \
  acc[MI0][2] = __builtin_amdgcn_mfma_i32_16x16x64_i8(b2, a0, acc[MI0][2], 0, 0, 0); \
  acc[MI0][3] = __builtin_amdgcn_mfma_i32_16x16x64_i8(b3, a0, acc[MI0][3], 0, 0, 0); \
  acc[MI1][0] = __builtin_amdgcn_mfma_i32_16x16x64_i8(b0, a1, acc[MI1][0], 0, 0, 0); \
  acc[MI1][1] = __builtin_amdgcn_mfma_i32_16x16x64_i8(b1, a1, acc[MI1][1], 0, 0, 0); \
  acc[MI1][2] = __builtin_amdgcn_mfma_i32_16x16x64_i8(b2, a1, acc[MI1][2], 0, 0, 0); \
  acc[MI1][3] = __builtin_amdgcn_mfma_i32_16x16x64_i8(b3, a1, acc[MI1][3], 0, 0, 0);

// ---------- GEMM1: h = gelu((qx·qw1^T + b1)·sx·sw1), f16 out + per-row amax ----------
// PHASE-SPLIT REWRITE (T3+T4+T5): 256x256 tile, 512 thr = 8 waves (2x4),
// wave-tile 128r x 64c, BK=64, 3x32KB buffers (96 KB, 1 block/CU).
// Per K-tile: entry {vmcnt(4) counted, barrier}, then 4 phases each
// {ds_reads + 1 gl_lds issue -> lgkmcnt(0) -> setprio(1) -> 8 MFMA ->
//  setprio(0) -> barrier}. vmcnt never drains to 0 mid-loop (T4).
// 8 waves/block per m232 lesson (4-wave 8-phase = null).
__global__ __launch_bounds__(512, 2) void gemm1_i8(
    const signed char* __restrict__ A, const signed char* __restrict__ B,
    const float* __restrict__ bias, const float* __restrict__ sA,
    const unsigned* __restrict__ sBbits, _Float16* __restrict__ out,
    unsigned* __restrict__ amax_out, int N, int K, int Mout) {
  __shared__ __align__(16) signed char lds[3 * 32768];  // per buf: A 16K | B 16K

  const int t = threadIdx.x;
  const int lane = t & 63;
  const int wv = t >> 6;     // 0..7
  const int wm = wv >> 2;    // 0..1 row half
  const int wn = wv & 3;     // 0..3 col quarter

  const int nwg = gridDim.x * gridDim.y;
  const int wg = xcd_swizzle(blockIdx.x + gridDim.x * blockIdx.y, nwg);
  const int colBlk = (wg % gridDim.x) * 256;
  const int rowBlk = (wg / gridDim.x) * 256;

  const int kb = (((lane & 3) ^ ((lane >> 3) & 3)) * 16);
  const int rr = lane >> 2;

  // 32 x 1KB chunks/buf: c<16 = A rows [c*16..c*16+16), else B rows.
  // Wave stages c = wv + 8j, j=0..3 (2 A-chunks + 2 B-chunks).
  const signed char* gp[4];
  int ldo[4];
#pragma unroll
  for (int j = 0; j < 4; j++) {
    const int c = wv + 8 * j;
    if (c < 16) {
      int r = rowBlk + c * 16 + rr;
      if (r > N - 1) r = N - 1;
      gp[j] = A + (size_t)r * K + kb;
      ldo[j] = c * 1024;
    } else {
      const int r = colBlk + (c - 16) * 16 + rr;   // < 3072 always
      gp[j] = B + (size_t)r * K + kb;
      ldo[j] = 16384 + (c - 16) * 1024;
    }
  }

  const v4i vzero = {0, 0, 0, 0};
  v4i acc[8][4];
#pragma unroll
  for (int i = 0; i < 8; i++)
#pragma unroll
    for (int j = 0; j < 4; j++) acc[i][j] = vzero;

  const int swz = ((lane >> 4) ^ ((lane >> 1) & 3)) * 16;
  const int aoff = (wm * 128 + (lane & 15)) * 64 + swz;          // + mi*1024
  const int boff = 16384 + (wn * 64 + (lane & 15)) * 64 + swz;   // + ni*1024

  const int T = K >> 6;   // 12

  auto issue1 = [&](int bufo, int j) {
    gl2lds16(gp[j], lds + bufo + ldo[j]);
    gp[j] += 64;
  };

#pragma unroll
  for (int j = 0; j < 4; j++) issue1(0, j);
#pragma unroll
  for (int j = 0; j < 4; j++) issue1(32768, j);

  int cur = 0;
  for (int kt = 0; kt < T; ++kt) {
    // ---- tile entry: counted vmcnt gate + barrier ----
    asm volatile("" ::: "memory");
    if (kt < T - 1)
      __builtin_amdgcn_s_waitcnt(0x0074);  // vmcnt(4) lgkmcnt(0)
    else
      __builtin_amdgcn_s_waitcnt(0x0070);  // vmcnt(0) lgkmcnt(0)
    __builtin_amdgcn_s_barrier();
    asm volatile("" ::: "memory");

    const bool pf = (kt + 2 < T);
    int pfo = cur + 65536;
    if (pfo >= 98304) pfo -= 98304;

    v4i a0, a1, b0, b1, b2, b3;

    // ---- phase 0: B frags + a(0,1); issue chunk 0; MFMA mi=0,1 ----
    b0 = *(const v4i*)(lds + cur + boff);
    b1 = *(const v4i*)(lds + cur + boff + 1024);
    b2 = *(const v4i*)(lds + cur + boff + 2048);
    b3 = *(const v4i*)(lds + cur + boff + 3072);
    a0 = *(const v4i*)(lds + cur + aoff);
    a1 = *(const v4i*)(lds + cur + aoff + 1024);
    if (pf) issue1(pfo, 0);
    asm volatile("" ::: "memory");
    __builtin_amdgcn_s_waitcnt(0xC07F);  // lgkmcnt(0) only
    __builtin_amdgcn_s_setprio(1);
    PHASE_MMA(0, 1)
    __builtin_amdgcn_s_setprio(0);
    asm volatile("" ::: "memory");
    __builtin_amdgcn_s_barrier();
    asm volatile("" ::: "memory");

    // ---- phase 1: a(2,3); issue chunk 1; MFMA mi=2,3 ----
    a0 = *(const v4i*)(lds + cur + aoff + 2048);
    a1 = *(const v4i*)(lds + cur + aoff + 3072);
    if (pf) issue1(pfo, 1);
    asm volatile("" ::: "memory");
    __builtin_amdgcn_s_waitcnt(0xC07F);
    __builtin_amdgcn_s_setprio(1);
    PHASE_MMA(2, 3)
    __builtin_amdgcn_s_setprio(0);
    asm volatile("" ::: "memory");
    __builtin_amdgcn_s_barrier();
    asm volatile("" ::: "memory");

    // ---- phase 2: a(4,5); issue chunk 2; MFMA mi=4,5 ----
    a0 = *(const v4i*)(lds + cur + aoff + 4096);
    a1 = *(const v4i*)(lds + cur + aoff + 5120);
    if (pf) issue1(pfo, 2);
    asm volatile("" ::: "memory");
    __builtin_amdgcn_s_waitcnt(0xC07F);
    __builtin_amdgcn_s_setprio(1);
    PHASE_MMA(4, 5)
    __builtin_amdgcn_s_setprio(0);
    asm volatile("" ::: "memory");
    __builtin_amdgcn_s_barrier();
    asm volatile("" ::: "memory");

    // ---- phase 3: a(6,7); issue chunk 3; MFMA mi=6,7 (no trailing barrier;
    //      next tile's entry barrier covers buffer-reuse safety) ----
    a0 = *(const v4i*)(lds + cur + aoff + 6144);
    a1 = *(const v4i*)(lds + cur + aoff + 7168);
    if (pf) issue1(pfo, 3);
    asm volatile("" ::: "memory");
    __builtin_amdgcn_s_waitcnt(0xC07F);
    __builtin_amdgcn_s_setprio(1);
    PHASE_MMA(6, 7)
    __builtin_amdgcn_s_setprio(0);

    cur += 32768;
    if (cur >= 98304) cur = 0;
  }

  // ---- epilogue: lane owns token (rowBlk+wm*128+mi*16+(lane&15)),
  //      cols col0+ni*16 .. +3 where col0 = colBlk+wn*64+quad*4 ----
  const float sB = fmaxf(__uint_as_float(*sBbits), MINR) / QPF;
  const int col0 = colBlk + wn * 64 + (lane >> 4) * 4;

  f4v bv[4];
#pragma unroll
  for (int ni = 0; ni < 4; ni++) bv[ni] = *(const f4v*)(bias + col0 + ni * 16);

#pragma unroll
  for (int mi = 0; mi < 8; mi++) {
    const int grow = rowBlk + wm * 128 + mi * 16 + (lane & 15);
    const float ss = ((grow < N) ? sA[grow] : 0.f) * sB;
    float rmax = 0.f;
#pragma unroll
    for (int ni = 0; ni < 4; ni++) {
      h4v hv;
#pragma unroll
      for (int r = 0; r < 4; r++) {
        float v = ((float)acc[mi][ni][r] + bv[ni][r]) * ss;
        v = gelu_exact(v);
        rmax = fmaxf(rmax, fabsf(v));
        hv[r] = (_Float16)v;
      }
      if (grow < N)
        *(h4v*)(out + (size_t)grow * Mout + col0 + ni * 16) = hv;
    }
    rmax = fmaxf(rmax, __shfl_xor(rmax, 16, 64));
    rmax = fmaxf(rmax, __shfl_xor(rmax, 32, 64));
    if (lane < 16 && grow < N)
      atomicMax(amax_out + grow, __float_as_uint(rmax));
  }
}

// ---------- GEMM2: out = (qh·qw2^T + b2)·sh·sw2, f32 out ----------
// 256 rows x 128 cols tile, 256 thr 2x2 waves (wave = 128r x 64c), BK=64,
// 3-buffer vmcnt(6) pipeline, XCD swizzle. UNCHANGED from R4 (attribution).
__global__ __launch_bounds__(256, 2) void gemm2_i8(
    const signed char* __restrict__ A, const signed char* __restrict__ B,
    const float* __restrict__ bias, const float* __restrict__ sA,
    const unsigned* __restrict__ sBbits, float* __restrict__ out,
    int N, int K, int Mout) {
  __shared__ __align__(16) signed char lds[3 * 24576];  // per buf: A 16K | B 8K

  const int t = threadIdx.x;
  const int lane = t & 63;
  const int wv = t >> 6;
  const int wm = wv >> 1;
  const int wn = wv & 1;

  const int nwg = gridDim.x * gridDim.y;
  const int wg = xcd_swizzle(blockIdx.x + gridDim.x * blockIdx.y, nwg);
  const int colBlk = (wg % gridDim.x) * 128;   // < Mout=768 always
  const int rowBlk = (wg / gridDim.x) * 256;

  const int kb = (((lane & 3) ^ ((lane >> 3) & 3)) * 16);
  const int rr = lane >> 2;

  // 24 x 1KB chunks: c<16 = A rows, else B rows. 6 chunks per wave.
  const signed char* gp[6];
  int ldo[6];
#pragma unroll
  for (int j = 0; j < 6; j++) {
    const int c = wv + 4 * j;
    if (c < 16) {
      int r = rowBlk + c * 16 + rr;
      if (r > N - 1) r = N - 1;
      gp[j] = A + (size_t)r * K + kb;
      ldo[j] = c * 1024;
    } else {
      const int r = colBlk + (c - 16) * 16 + rr;  // <= 767
      gp[j] = B + (size_t)r * K + kb;
      ldo[j] = 16384 + (c - 16) * 1024;
    }
  }

  const v4i vzero = {0, 0, 0, 0};
  v4i acc[8][4];
#pragma unroll
  for (int i = 0; i < 8; i++)
#pragma unroll
    for (int j = 0; j < 4; j++) acc[i][j] = vzero;

  const int swz = ((lane >> 4) ^ ((lane >> 1) & 3)) * 16;
  const int aoff = (wm * 128 + (lane & 15)) * 64 + swz;
  const int boff = 16384 + (wn * 64 + (lane & 15)) * 64 + swz;

  const int T = K >> 6;   // 48

  auto issue = [&](int bufo) {
#pragma unroll
    for (int j = 0; j < 6; j++) {
      gl2lds16(gp[j], lds + bufo + ldo[j]);
      gp[j] += 64;
    }
  };

  issue(0);
  issue(24576);

  int cur = 0;
  for (int kt = 0; kt < T; ++kt) {
    asm volatile("" ::: "memory");
    if (kt < T - 1)
      __builtin_amdgcn_s_waitcnt(0x0076);  // vmcnt(6) lgkmcnt(0)
    else
      __builtin_amdgcn_s_waitcnt(0x0070);  // vmcnt(0) lgkmcnt(0)
    __builtin_amdgcn_s_barrier();
    asm volatile("" ::: "memory");

    if (kt + 2 < T) {
      int pf = cur + 49152;
      if (pf >= 73728) pf -= 73728;
      issue(pf);
    }

    v4i a[8], b[4];
#pragma unroll
    for (int mi = 0; mi < 8; mi++)
      a[mi] = *(const v4i*)(lds + cur + aoff + mi * 1024);
#pragma unroll
    for (int ni = 0; ni < 4; ni++)
      b[ni] = *(const v4i*)(lds + cur + boff + ni * 1024);
#pragma unroll
    for (int mi = 0; mi < 8; mi++)
#pragma unroll
      for (int ni = 0; ni < 4; ni++)
        acc[mi][ni] = __builtin_amdgcn_mfma_i32_16x16x64_i8(b[ni], a[mi],
                                                            acc[mi][ni], 0, 0, 0);
    cur += 24576;
    if (cur >= 73728) cur = 0;
  }

  // ---- epilogue: direct dwordx4 f32 stores ----
  const float sB = fmaxf(__uint_as_float(*sBbits), MINR) / QPF;
  const int col0 = colBlk + wn * 64 + (lane >> 4) * 4;

  f4v bv[4];
#pragma unroll
  for (int ni = 0; ni < 4; ni++) bv[ni] = *(const f4v*)(bias + col0 + ni * 16);

#pragma unroll
  for (int mi = 0; mi < 8; mi++) {
    const int grow = rowBlk + wm * 128 + mi * 16 + (lane & 15);
    const float ss = ((grow < N) ? sA[grow] : 0.f) * sB;
#pragma unroll
    for (int ni = 0; ni < 4; ni++) {
      f4v o;
#pragma unroll
      for (int r = 0; r < 4; r++)
        o[r] = ((float)acc[mi][ni][r] + bv[ni][r]) * ss;
      if (grow < N)
        *(f4v*)(out + (size_t)grow * Mout + col0 + ni * 16) = o;
    }
  }
}

extern "C" void kernel_launch(void* const* d_in, const int* in_sizes, int n_in,
                              void* d_out, int out_size, void* d_ws, size_t ws_size,
                              hipStream_t stream) {
  const float* x  = (const float*)d_in[0];
  const float* w1 = (const float*)d_in[1];
  const float* b1 = (const float*)d_in[2];
  const float* w2 = (const float*)d_in[3];
  const float* b2 = (const float*)d_in[4];

  const int H = in_sizes[2];        // 3072
  const int D = in_sizes[4];        // 768
  const int N = in_sizes[0] / D;    // 12608 tokens
  float* out = (float*)d_out;

  char* ws = (char*)d_ws;
  auto alloc = [&](size_t bytes) {
    char* p = ws;
    ws += (bytes + 255) & ~(size_t)255;
    return p;
  };
  signed char* qx  = (signed char*)alloc((size_t)N * D);
  signed char* qw1 = (signed char*)alloc((size_t)H * D);
  signed char* qw2 = (signed char*)alloc((size_t)H * D);
  signed char* qh  = (signed char*)alloc((size_t)N * H);
  float*    sx     = (float*)alloc((size_t)N * 4);
  float*    sh     = (float*)alloc((size_t)N * 4);
  unsigned* amaxh  = (unsigned*)alloc((size_t)N * 4);
  unsigned* wamax  = (unsigned*)alloc(256);
  float*    partial= (float*)alloc(1024 * 4);
  _Float16* h      = (_Float16*)alloc((size_t)N * H * 2);
  (void)ws_size;

  const int n4w = (H * D) >> 2;

  pre_kernel<<<1024 + (N + 3) / 4, 256, 0, stream>>>(w1, w2, n4w, x, qx, sx,
                                                     amaxh, partial, D, N);
  wquant2_kernel<<<dim3(512, 2), 256, 0, stream>>>(w1, w2, n4w, partial, wamax,
                                                   qw1, qw2);

  dim3 g1(H / 256, (N + 255) / 256);
  gemm1_i8<<<g1, 512, 0, stream>>>(qx, qw1, b1, sx, wamax + 0, h, amaxh,
                                   N, D, H);
  hquant4_kernel<<<N / 4, 256, 0, stream>>>(h, amaxh, qh, sh, H);

  dim3 g2(D / 128, (N + 255) / 256);
  gemm2_i8<<<g2, 256, 0, stream>>>(qh, qw2, b2, sh, wamax + 1, out, N, H, D);
}

// Round 7
// 238.328 us; speedup vs baseline: 1.0597x; 1.0597x over previous
//
#include <hip/hip_runtime.h>
#include <stdint.h>

#define QPF  127.0f
#define MINR 1e-6f

typedef int v4i __attribute__((ext_vector_type(4)));
typedef float f4v __attribute__((ext_vector_type(4)));
typedef _Float16 h4v __attribute__((ext_vector_type(4)));
typedef _Float16 h8 __attribute__((ext_vector_type(8)));
typedef signed char c8 __attribute__((ext_vector_type(8)));

// ---------- helpers ----------
__device__ __forceinline__ float wave_max64(float v) {
  v = fmaxf(v, __shfl_xor(v, 32, 64));
  v = fmaxf(v, __shfl_xor(v, 16, 64));
  v = fmaxf(v, __shfl_xor(v, 8, 64));
  v = fmaxf(v, __shfl_xor(v, 4, 64));
  v = fmaxf(v, __shfl_xor(v, 2, 64));
  v = fmaxf(v, __shfl_xor(v, 1, 64));
  return v;
}

// Exact-GELU via A&S 7.1.26 erf (|eps| <= 1.5e-7), branchless.
__device__ __forceinline__ float gelu_exact(float x) {
  float z = fabsf(x) * 0.70710678118654752440f;
  float t = __builtin_amdgcn_rcpf(fmaf(0.3275911f, z, 1.0f));
  float p = fmaf(fmaf(fmaf(fmaf(1.061405429f, t, -1.453152027f), t,
                           1.421413741f), t, -0.284496736f), t, 0.254829592f) * t;
  float e = __expf(-z * z);
  float erfz = fmaf(-p, e, 1.0f);
  float cdf = fmaf(0.5f, copysignf(erfz, x), 0.5f);
  return x * cdf;
}

// async global->LDS, 16B per lane; LDS dest is wave-uniform base + lane*16
__device__ __forceinline__ void gl2lds16(const void* g, void* l) {
  __builtin_amdgcn_global_load_lds(
      (const __attribute__((address_space(1))) int*)g,
      (__attribute__((address_space(3))) int*)l,
      16, 0, 0);
}

// XCD-aware bijective block remap (T1, m204 variant).
__device__ __forceinline__ int xcd_swizzle(int flat, int nwg) {
  const int xcd = flat & 7;
  const int idx = flat >> 3;
  const int q = nwg >> 3, r = nwg & 7;
  const int base = (xcd < r) ? xcd * (q + 1) : r * (q + 1) + (xcd - r) * q;
  return base + idx;
}

// ---------- fused pre-pass: w1/w2 amax partials + per-token x quant + amaxh zero ----
__global__ __launch_bounds__(256) void pre_kernel(
    const float* __restrict__ w1, const float* __restrict__ w2, int n4,
    const float* __restrict__ x, signed char* __restrict__ qx,
    float* __restrict__ sx, unsigned* __restrict__ amaxh,
    float* __restrict__ partial, int K, int nTok) {
  __shared__ float red[4];
  const int b = blockIdx.x;
  const int tid = threadIdx.x;
  const int lane = tid & 63, wvi = tid >> 6;

  if (b < 1024) {
    const float4* w4 = (const float4*)(b < 512 ? w1 : w2);
    const int bb = b & 511;
    float m = 0.f;
    for (int i = bb * 256 + tid; i < n4; i += 512 * 256) {
      float4 v = w4[i];
      m = fmaxf(m, fmaxf(fmaxf(fabsf(v.x), fabsf(v.y)),
                         fmaxf(fabsf(v.z), fabsf(v.w))));
    }
    m = wave_max64(m);
    if (lane == 0) red[wvi] = m;
    __syncthreads();
    if (tid == 0)
      partial[b] = fmaxf(fmaxf(red[0], red[1]), fmaxf(red[2], red[3]));
  } else {
    const int token = (b - 1024) * 4 + wvi;
    if (token < nTok) {
      const int k4 = K >> 2;  // 192 for D=768
      const float4* xr = (const float4*)(x + (size_t)token * K);
      float m = 0.f;
      for (int i = lane; i < k4; i += 64) {
        float4 v = xr[i];
        m = fmaxf(m, fmaxf(fmaxf(fabsf(v.x), fabsf(v.y)),
                           fmaxf(fabsf(v.z), fabsf(v.w))));
      }
      m = wave_max64(m);
      const float s = fmaxf(m, MINR) / QPF;
      const float rs = 1.0f / s;
      if (lane == 0) { sx[token] = s; amaxh[token] = 0u; }
      char4* q4 = (char4*)(qx + (size_t)token * K);
      for (int i = lane; i < k4; i += 64) {
        float4 v = xr[i];  // L1-hot reload
        char4 c;
        c.x = (signed char)(int)rintf(v.x * rs);
        c.y = (signed char)(int)rintf(v.y * rs);
        c.z = (signed char)(int)rintf(v.z * rs);
        c.w = (signed char)(int)rintf(v.w * rs);
        q4[i] = c;
      }
    }
  }
}

// ---------- weight quantize (reduces 512 partials itself; y selects tensor) ----------
__global__ __launch_bounds__(256) void wquant2_kernel(
    const float* __restrict__ w1, const float* __restrict__ w2, int n4,
    const float* __restrict__ partial, unsigned* __restrict__ wamax,
    signed char* __restrict__ q1, signed char* __restrict__ q2) {
  __shared__ float red[4];
  const int tid = threadIdx.x;
  const int lane = tid & 63, wvi = tid >> 6;
  const int y = blockIdx.y;
  float m = fmaxf(partial[y * 512 + tid], partial[y * 512 + 256 + tid]);
  m = wave_max64(m);
  if (lane == 0) red[wvi] = m;
  __syncthreads();
  const float M = fmaxf(fmaxf(red[0], red[1]), fmaxf(red[2], red[3]));
  if (blockIdx.x == 0 && tid == 0) wamax[y] = __float_as_uint(M);
  const float s = fmaxf(M, MINR) / QPF;
  const float rs = 1.0f / s;
  const float4* w4 = (const float4*)(y ? w2 : w1);
  char4* q4 = (char4*)(y ? q2 : q1);
  for (int i = blockIdx.x * 256 + tid; i < n4; i += gridDim.x * 256) {
    float4 v = w4[i];
    char4 c;
    c.x = (signed char)(int)rintf(v.x * rs);
    c.y = (signed char)(int)rintf(v.y * rs);
    c.z = (signed char)(int)rintf(v.z * rs);
    c.w = (signed char)(int)rintf(v.w * rs);
    q4[i] = c;
  }
}

// ---------- per-token h quantize: 4 tokens/block, one wave each ----------
__global__ __launch_bounds__(256) void hquant4_kernel(
    const _Float16* __restrict__ h, const unsigned* __restrict__ amaxbits,
    signed char* __restrict__ qh, float* __restrict__ sh, int K) {
  const int token = blockIdx.x * 4 + (threadIdx.x >> 6);
  const int lane = threadIdx.x & 63;
  const float s = fmaxf(__uint_as_float(amaxbits[token]), MINR) / QPF;
  const float rs = 1.0f / s;
  if (lane == 0) sh[token] = s;
  const h8* hr = (const h8*)(h + (size_t)token * K);
  c8* qr = (c8*)(qh + (size_t)token * K);
  for (int i = lane; i < (K >> 3); i += 64) {
    h8 v = hr[i];
    c8 c;
#pragma unroll
    for (int j = 0; j < 8; j++)
      c[j] = (signed char)(int)rintf((float)v[j] * rs);
    qr[i] = c;
  }
}

// ---------- GEMM1: h = gelu((qx·qw1^T + b1)·sx·sw1), f16 out + per-row amax ----------
// OCCUPANCY REBUILD: 128x128 tile, 4 waves 2x2, BK=64, XOR-swizzled LDS, but
// TWO 16KB buffers (32 KB total) -> 5 blocks/CU LDS-wise (was 48-96 KB = 1-2).
// R3-R5 ablation: tile size & phase-split don't move gemm1 (66/66/77 us);
// epilogue VALU (~13us chip) ~ K-loop MFMA (~15us) -> need cross-block overlap,
// i.e. residency. Counted vmcnt(4); second barrier per K-step for 2-buf safety.
__global__ __launch_bounds__(256, 4) void gemm1_i8(
    const signed char* __restrict__ A, const signed char* __restrict__ B,
    const float* __restrict__ bias, const float* __restrict__ sA,
    const unsigned* __restrict__ sBbits, _Float16* __restrict__ out,
    unsigned* __restrict__ amax_out, int N, int K, int Mout) {
  __shared__ __align__(16) signed char lds[2 * 16384];

  const int t = threadIdx.x;
  const int lane = t & 63;
  const int wv = t >> 6;
  const int wm = wv >> 1;
  const int wn = wv & 1;

  const int nwg = gridDim.x * gridDim.y;
  const int wg = xcd_swizzle(blockIdx.x + gridDim.x * blockIdx.y, nwg);
  const int colBlk = (wg % gridDim.x) * 128;
  const int rowBlk = (wg / gridDim.x) * 128;

  int ar0 = rowBlk + wv * 16 + (lane >> 2);
  int ar1 = ar0 + 64;
  if (ar0 > N - 1) ar0 = N - 1;
  if (ar1 > N - 1) ar1 = N - 1;
  const int br0 = colBlk + wv * 16 + (lane >> 2);
  const int br1 = br0 + 64;
  const int kb = (((lane & 3) ^ ((lane >> 3) & 3)) * 16);

  const signed char* gA0 = A + (size_t)ar0 * K + kb;
  const signed char* gA1 = A + (size_t)ar1 * K + kb;
  const signed char* gB0 = B + (size_t)br0 * K + kb;
  const signed char* gB1 = B + (size_t)br1 * K + kb;

  const v4i vzero = {0, 0, 0, 0};
  v4i acc[4][4];
#pragma unroll
  for (int i = 0; i < 4; i++)
#pragma unroll
    for (int j = 0; j < 4; j++) acc[i][j] = vzero;

  const int swz = ((lane >> 4) ^ ((lane >> 1) & 3)) * 16;
  const int aoff = (wm * 64 + (lane & 15)) * 64 + swz;
  const int boff = (wn * 64 + (lane & 15)) * 64 + swz + 8192;

  const int T = K >> 6;   // 12

  auto issue = [&](int bufo) {
    signed char* a = lds + bufo + wv * 1024;
    gl2lds16(gA0, a);
    gl2lds16(gA1, a + 4096);
    gl2lds16(gB0, a + 8192);
    gl2lds16(gB1, a + 12288);
    gA0 += 64; gA1 += 64; gB0 += 64; gB1 += 64;
  };

  issue(0);
  issue(16384);

  int cur = 0;
  for (int kt = 0; kt < T; ++kt) {
    asm volatile("" ::: "memory");
    if (kt < T - 1)
      __builtin_amdgcn_s_waitcnt(0x0074);  // vmcnt(4) lgkmcnt(0)
    else
      __builtin_amdgcn_s_waitcnt(0x0070);  // vmcnt(0) lgkmcnt(0)
    __builtin_amdgcn_s_barrier();
    asm volatile("" ::: "memory");

    v4i a[4], b[4];
#pragma unroll
    for (int mi = 0; mi < 4; mi++)
      a[mi] = *(const v4i*)(lds + cur + aoff + mi * 1024);
#pragma unroll
    for (int ni = 0; ni < 4; ni++)
      b[ni] = *(const v4i*)(lds + cur + boff + ni * 1024);

    // all waves done reading cur before overwriting it with tile kt+2
    asm volatile("" ::: "memory");
    __builtin_amdgcn_s_waitcnt(0xC07F);  // lgkmcnt(0)
    __builtin_amdgcn_s_barrier();
    asm volatile("" ::: "memory");
    if (kt + 2 < T) issue(cur);

    // swapped operands: acc cols <- token (lane&15), acc rows <- weight col
#pragma unroll
    for (int mi = 0; mi < 4; mi++)
#pragma unroll
      for (int ni = 0; ni < 4; ni++)
        acc[mi][ni] = __builtin_amdgcn_mfma_i32_16x16x64_i8(b[ni], a[mi],
                                                            acc[mi][ni], 0, 0, 0);
    cur ^= 16384;
  }

  // ---- epilogue: lane owns token (rowBlk+wm*64+mi*16+(lane&15)),
  //      cols col0+ni*16 .. +3 where col0 = colBlk+wn*64+quad*4 ----
  const float sB = fmaxf(__uint_as_float(*sBbits), MINR) / QPF;
  const int col0 = colBlk + wn * 64 + (lane >> 4) * 4;

  f4v bv[4];
#pragma unroll
  for (int ni = 0; ni < 4; ni++) bv[ni] = *(const f4v*)(bias + col0 + ni * 16);

#pragma unroll
  for (int mi = 0; mi < 4; mi++) {
    const int grow = rowBlk + wm * 64 + mi * 16 + (lane & 15);
    const float ss = ((grow < N) ? sA[grow] : 0.f) * sB;
    float rmax = 0.f;
#pragma unroll
    for (int ni = 0; ni < 4; ni++) {
      h4v hv;
#pragma unroll
      for (int r = 0; r < 4; r++) {
        float v = ((float)acc[mi][ni][r] + bv[ni][r]) * ss;
        v = gelu_exact(v);
        rmax = fmaxf(rmax, fabsf(v));
        hv[r] = (_Float16)v;
      }
      if (grow < N)
        *(h4v*)(out + (size_t)grow * Mout + col0 + ni * 16) = hv;
    }
    rmax = fmaxf(rmax, __shfl_xor(rmax, 16, 64));
    rmax = fmaxf(rmax, __shfl_xor(rmax, 32, 64));
    if (lane < 16 && grow < N)
      atomicMax(amax_out + grow, __float_as_uint(rmax));
  }
}

// ---------- GEMM2: out = (qh·qw2^T + b2)·sh·sw2, f32 out ----------
// Same occupancy rebuild: 128x128 tile, 4 waves 2x2, 2x16KB buffers, counted
// vmcnt(4), 2 barriers/K-step, XCD swizzle. T=48.
__global__ __launch_bounds__(256, 4) void gemm2_i8(
    const signed char* __restrict__ A, const signed char* __restrict__ B,
    const float* __restrict__ bias, const float* __restrict__ sA,
    const unsigned* __restrict__ sBbits, float* __restrict__ out,
    int N, int K, int Mout) {
  __shared__ __align__(16) signed char lds[2 * 16384];

  const int t = threadIdx.x;
  const int lane = t & 63;
  const int wv = t >> 6;
  const int wm = wv >> 1;
  const int wn = wv & 1;

  const int nwg = gridDim.x * gridDim.y;
  const int wg = xcd_swizzle(blockIdx.x + gridDim.x * blockIdx.y, nwg);
  const int colBlk = (wg % gridDim.x) * 128;   // < Mout=768 always
  const int rowBlk = (wg / gridDim.x) * 128;

  int ar0 = rowBlk + wv * 16 + (lane >> 2);
  int ar1 = ar0 + 64;
  if (ar0 > N - 1) ar0 = N - 1;
  if (ar1 > N - 1) ar1 = N - 1;
  const int br0 = colBlk + wv * 16 + (lane >> 2);  // <= 767, no clamp needed
  const int br1 = br0 + 64;
  const int kb = (((lane & 3) ^ ((lane >> 3) & 3)) * 16);

  const signed char* gA0 = A + (size_t)ar0 * K + kb;
  const signed char* gA1 = A + (size_t)ar1 * K + kb;
  const signed char* gB0 = B + (size_t)br0 * K + kb;
  const signed char* gB1 = B + (size_t)br1 * K + kb;

  const v4i vzero = {0, 0, 0, 0};
  v4i acc[4][4];
#pragma unroll
  for (int i = 0; i < 4; i++)
#pragma unroll
    for (int j = 0; j < 4; j++) acc[i][j] = vzero;

  const int swz = ((lane >> 4) ^ ((lane >> 1) & 3)) * 16;
  const int aoff = (wm * 64 + (lane & 15)) * 64 + swz;
  const int boff = (wn * 64 + (lane & 15)) * 64 + swz + 8192;

  const int T = K >> 6;   // 48

  auto issue = [&](int bufo) {
    signed char* a = lds + bufo + wv * 1024;
    gl2lds16(gA0, a);
    gl2lds16(gA1, a + 4096);
    gl2lds16(gB0, a + 8192);
    gl2lds16(gB1, a + 12288);
    gA0 += 64; gA1 += 64; gB0 += 64; gB1 += 64;
  };

  issue(0);
  issue(16384);

  int cur = 0;
  for (int kt = 0; kt < T; ++kt) {
    asm volatile("" ::: "memory");
    if (kt < T - 1)
      __builtin_amdgcn_s_waitcnt(0x0074);  // vmcnt(4) lgkmcnt(0)
    else
      __builtin_amdgcn_s_waitcnt(0x0070);  // vmcnt(0) lgkmcnt(0)
    __builtin_amdgcn_s_barrier();
    asm volatile("" ::: "memory");

    v4i a[4], b[4];
#pragma unroll
    for (int mi = 0; mi < 4; mi++)
      a[mi] = *(const v4i*)(lds + cur + aoff + mi * 1024);
#pragma unroll
    for (int ni = 0; ni < 4; ni++)
      b[ni] = *(const v4i*)(lds + cur + boff + ni * 1024);

    asm volatile("" ::: "memory");
    __builtin_amdgcn_s_waitcnt(0xC07F);  // lgkmcnt(0)
    __builtin_amdgcn_s_barrier();
    asm volatile("" ::: "memory");
    if (kt + 2 < T) issue(cur);

#pragma unroll
    for (int mi = 0; mi < 4; mi++)
#pragma unroll
      for (int ni = 0; ni < 4; ni++)
        acc[mi][ni] = __builtin_amdgcn_mfma_i32_16x16x64_i8(b[ni], a[mi],
                                                            acc[mi][ni], 0, 0, 0);
    cur ^= 16384;
  }

  // ---- epilogue: direct dwordx4 f32 stores ----
  const float sB = fmaxf(__uint_as_float(*sBbits), MINR) / QPF;
  const int col0 = colBlk + wn * 64 + (lane >> 4) * 4;

  f4v bv[4];
#pragma unroll
  for (int ni = 0; ni < 4; ni++) bv[ni] = *(const f4v*)(bias + col0 + ni * 16);

#pragma unroll
  for (int mi = 0; mi < 4; mi++) {
    const int grow = rowBlk + wm * 64 + mi * 16 + (lane & 15);
    const float ss = ((grow < N) ? sA[grow] : 0.f) * sB;
#pragma unroll
    for (int ni = 0; ni < 4; ni++) {
      f4v o;
#pragma unroll
      for (int r = 0; r < 4; r++)
        o[r] = ((float)acc[mi][ni][r] + bv[ni][r]) * ss;
      if (grow < N)
        *(f4v*)(out + (size_t)grow * Mout + col0 + ni * 16) = o;
    }
  }
}

extern "C" void kernel_launch(void* const* d_in, const int* in_sizes, int n_in,
                              void* d_out, int out_size, void* d_ws, size_t ws_size,
                              hipStream_t stream) {
  const float* x  = (const float*)d_in[0];
  const float* w1 = (const float*)d_in[1];
  const float* b1 = (const float*)d_in[2];
  const float* w2 = (const float*)d_in[3];
  const float* b2 = (const float*)d_in[4];

  const int H = in_sizes[2];        // 3072
  const int D = in_sizes[4];        // 768
  const int N = in_sizes[0] / D;    // 12608 tokens
  float* out = (float*)d_out;

  char* ws = (char*)d_ws;
  auto alloc = [&](size_t bytes) {
    char* p = ws;
    ws += (bytes + 255) & ~(size_t)255;
    return p;
  };
  signed char* qx  = (signed char*)alloc((size_t)N * D);
  signed char* qw1 = (signed char*)alloc((size_t)H * D);
  signed char* qw2 = (signed char*)alloc((size_t)H * D);
  signed char* qh  = (signed char*)alloc((size_t)N * H);
  float*    sx     = (float*)alloc((size_t)N * 4);
  float*    sh     = (float*)alloc((size_t)N * 4);
  unsigned* amaxh  = (unsigned*)alloc((size_t)N * 4);
  unsigned* wamax  = (unsigned*)alloc(256);
  float*    partial= (float*)alloc(1024 * 4);
  _Float16* h      = (_Float16*)alloc((size_t)N * H * 2);
  (void)ws_size;

  const int n4w = (H * D) >> 2;

  pre_kernel<<<1024 + (N + 3) / 4, 256, 0, stream>>>(w1, w2, n4w, x, qx, sx,
                                                     amaxh, partial, D, N);
  wquant2_kernel<<<dim3(512, 2), 256, 0, stream>>>(w1, w2, n4w, partial, wamax,
                                                   qw1, qw2);

  dim3 g1(H / 128, (N + 127) / 128);
  gemm1_i8<<<g1, 256, 0, stream>>>(qx, qw1, b1, sx, wamax + 0, h, amaxh,
                                   N, D, H);
  hquant4_kernel<<<N / 4, 256, 0, stream>>>(h, amaxh, qh, sh, H);

  dim3 g2(D / 128, (N + 127) / 128);
  gemm2_i8<<<g2, 256, 0, stream>>>(qh, qw2, b2, sh, wamax + 1, out, N, H, D);
}